// Round 5
// baseline (347.213 us; speedup 1.0000x reference)
//
#include <hip/hip_runtime.h>
#include <hip/hip_bf16.h>

// PointerNet: out[b][k] = sum_c C_k[b,c] * sigmoid(WP[b,c]+WC_k[b,c]+Gb[c]) * (WPo[b,c]+Ob[c])
//   GEMM A: WPcat = P @ [GateWeight_P | OutWeight]  (M=8192,N=2048,K=1024), output INTERLEAVED:
//           uint32 WPcat[b][c] = (bf16 wp, bf16 wpo) so the epilogue gets both in one load.
//   GEMM B: WC_k = C_k @ GateWeight_C fused with sigmoid/dot epilogue (atomicAdd out).
// R10: R9 post-mortem: conflicts=0 bought only 2us -> the binding term in the 2-barrier
//     skeleton is the vmcnt(0) drain at each barrier, which is only covered when OTHER
//     independent barrier groups are resident (m114). Our 512-thr/8-wave blocks left
//     ~1.5 groups/CU. Reshape (parameter change only, no sync edits) to the m103-proven
//     128x128 / 256-thr / 4-wave shape: 16KB LDS -> ~4 independent 4-wave groups/CU.
//     learn_hip tile-space at this structure: 128^2 = 912 TF vs 128x256 = 823 TF.
//     Kept: conflict-free swizzle (R7/R9, SQ_LDS_BANK_CONFLICT == 0), gl_lds staging,
//     interleaved-WPcat epilogue with hoisted Gb/Ob.

#define B_  8192
#define PD_ 1024
#define CD_ 1024

typedef unsigned short ushort_t;
typedef unsigned int   uint_t;
typedef __attribute__((ext_vector_type(8))) short    short8;
typedef __attribute__((ext_vector_type(4))) float    floatx4;

__device__ __forceinline__ float bf2f(unsigned short u) {
    return __uint_as_float(((unsigned)u) << 16);
}
__device__ __forceinline__ unsigned short f2bf(float f) {
    unsigned u = __float_as_uint(f);
    unsigned r = u + 0x7FFFu + ((u >> 16) & 1u);   // RNE
    return (unsigned short)(r >> 16);
}

// ---------------- prep: cast P,C1..C4 -> bf16; transpose 3 weights; zero out ----------------
__global__ __launch_bounds__(256) void prep_kernel(const float* __restrict__ P,
                                                   const float* __restrict__ C1,
                                                   const float* __restrict__ C2,
                                                   const float* __restrict__ C3,
                                                   const float* __restrict__ C4,
                                                   const float* __restrict__ GWP,
                                                   const float* __restrict__ OW,
                                                   const float* __restrict__ GWC,
                                                   ushort_t* __restrict__ Pb,
                                                   ushort_t* __restrict__ Call,
                                                   ushort_t* __restrict__ Wcat,
                                                   ushort_t* __restrict__ GWCt,
                                                   float* __restrict__ out) {
    const int bid = blockIdx.x;
    const int tid = threadIdx.x;
    if (bid < 40960) {
        const int seg = bid >> 13;
        const int i   = (bid & 8191) * 256 + tid;
        const float* src;
        ushort_t* dst;
        switch (seg) {
            case 0: src = P;  dst = Pb; break;
            case 1: src = C1; dst = Call; break;
            case 2: src = C2; dst = Call + (size_t)1 * B_ * CD_; break;
            case 3: src = C3; dst = Call + (size_t)2 * B_ * CD_; break;
            default: src = C4; dst = Call + (size_t)3 * B_ * CD_; break;
        }
        float4 v = ((const float4*)src)[i];
        ushort4 o;
        o.x = f2bf(v.x); o.y = f2bf(v.y); o.z = f2bf(v.z); o.w = f2bf(v.w);
        ((ushort4*)dst)[i] = o;
    } else if (bid < 44032) {
        __shared__ float tile[32][33];
        const int tb  = bid - 40960;
        const int seg = tb >> 10;
        const int t32 = tb & 1023;
        const float* src;
        ushort_t* dst;
        switch (seg) {
            case 0: src = GWP; dst = Wcat; break;
            case 1: src = OW;  dst = Wcat + 1024 * 1024; break;
            default: src = GWC; dst = GWCt; break;
        }
        const int c0 = (t32 & 31) * 32, r0 = (t32 >> 5) * 32;
        const int x = tid & 31, y = tid >> 5;
        for (int i = y; i < 32; i += 8)
            tile[i][x] = src[(size_t)(r0 + i) * 1024 + c0 + x];
        __syncthreads();
        for (int i = y; i < 32; i += 8)
            dst[(size_t)(c0 + i) * 1024 + r0 + x] = f2bf(tile[x][i]);
    } else {
        const int i = (bid - 44032) * 256 + tid;
        ((float4*)out)[i] = float4{0.f, 0.f, 0.f, 0.f};
    }
}

__device__ __forceinline__ void gl_lds16(const void* g, void* l) {
    __builtin_amdgcn_global_load_lds((const __attribute__((address_space(1))) void*)g,
                                     (__attribute__((address_space(3))) void*)l, 16, 0, 0);
}

// ---------------- GEMM A: WPcat(interleaved) = Pb @ Wcat^T  (128x128 tile, 256 thr) ----------------
// grid 1024: xcd=bid&7, q=bid>>3; slab=(q>>4)*8+xcd (64 slabs), colt=q&15 (16 col tiles).
__global__ __launch_bounds__(256, 4) void gemmA(const ushort_t* __restrict__ A,
                                                const ushort_t* __restrict__ Bt,
                                                ushort_t* __restrict__ C) {
    __shared__ ushort_t smem[8192];       // lA 4096 + lB 4096 elems = 16 KB
    ushort_t* lA = smem;
    ushort_t* lB = smem + 4096;
    const int K = 1024;
    const int xcd = blockIdx.x & 7, q = blockIdx.x >> 3;
    const int tileM = ((q >> 4) * 8 + xcd) * 128;
    const int tileN = (q & 15) * 128;

    const int t = threadIdx.x;
    const int wave = t >> 6, lane = t & 63;
    const int quad = lane >> 4, l16 = lane & 15;
    const int wm = wave >> 1, wn = wave & 1;

    // staging: thread t, load j in {0,1} covers row (t>>2)+j*64, 16B slot (t&3);
    // global seg pre-swizzled (seg_g = slot ^ ((row>>1)&3), stable across j since
    // 64 ≡ 0 mod 8) so LDS dest stays linear (rule #21). Conflict-free (R7/R9).
    const int srow = t >> 2;
    const int sc   = ((t & 3) ^ ((t >> 3) & 3)) * 8;
    const ushort_t* Ag = A  + (size_t)(tileM + srow) * K + sc;
    const ushort_t* Bg = Bt + (size_t)(tileN + srow) * K + sc;
    const int lo = t * 8;
    const int fro = (l16 * 4 + (quad ^ ((l16 >> 1) & 3))) * 8;

    floatx4 acc[4][4];
#pragma unroll
    for (int i = 0; i < 4; i++)
#pragma unroll
        for (int j = 0; j < 4; j++) acc[i][j] = (floatx4)0.f;

    for (int k0 = 0; k0 < K; k0 += 32) {
        gl_lds16(Ag + k0,                   &lA[lo]);
        gl_lds16(Ag + (size_t)64 * K + k0,  &lA[lo + 2048]);
        gl_lds16(Bg + k0,                   &lB[lo]);
        gl_lds16(Bg + (size_t)64 * K + k0,  &lB[lo + 2048]);
        __syncthreads();
        short8 af[4], bfr[4];
#pragma unroll
        for (int mi = 0; mi < 4; mi++)
            af[mi] = *(const short8*)&lA[(wm * 4 + mi) * 512 + fro];
#pragma unroll
        for (int ni = 0; ni < 4; ni++)
            bfr[ni] = *(const short8*)&lB[(wn * 4 + ni) * 512 + fro];
#pragma unroll
        for (int mi = 0; mi < 4; mi++)
#pragma unroll
            for (int ni = 0; ni < 4; ni++)
                acc[mi][ni] = __builtin_amdgcn_mfma_f32_16x16x32_bf16(
                    af[mi], bfr[ni], acc[mi][ni], 0, 0, 0);
        __syncthreads();
    }
#pragma unroll
    for (int mi = 0; mi < 4; mi++)
#pragma unroll
        for (int ni = 0; ni < 4; ni++) {
            const int col = tileN + wn * 64 + ni * 16 + l16;
            const int ci = col & 1023, hi = col >> 10;    // interleave: (wp,wpo) per uint32
#pragma unroll
            for (int r = 0; r < 4; r++) {
                const int row = tileM + wm * 64 + mi * 16 + quad * 4 + r;
                C[(size_t)(row * 1024 + ci) * 2 + hi] = f2bf(acc[mi][ni][r]);
            }
        }
}

// ---------------- GEMM B + register-direct fused epilogue (128x128 tile, 256 thr) ----------------
// grid 2048: xcd=bid&7, q=bid>>3; slab=(q>>3)*8+xcd (256 slabs), colt=q&7 (8 col tiles).
// Lane owns C-fragment rows wm*64+mi*16+quad*4+r, col wn*64+ni*16+l16; it folds
// sigmoid/dot contributions straight out of acc (fp32), reduces across the 16-lane
// quad group, and l16==0 atomicAdds. acc never spills, WC never hits memory.
__global__ __launch_bounds__(256, 4) void gemmB_fused(const ushort_t* __restrict__ Call,
                                                      const ushort_t* __restrict__ GWCt,
                                                      const uint_t* __restrict__ WPcat,
                                                      const float* __restrict__ Gb,
                                                      const float* __restrict__ Ob,
                                                      float* __restrict__ out) {
    __shared__ ushort_t smem[8192];       // 16 KB staging
    ushort_t* lA = smem;
    ushort_t* lB = smem + 4096;
    const int K = 1024;
    const int xcd = blockIdx.x & 7, q = blockIdx.x >> 3;
    const int tileM = ((q >> 3) * 8 + xcd) * 128;
    const int tileN = (q & 7) * 128;

    const int t = threadIdx.x;
    const int wave = t >> 6, lane = t & 63;
    const int quad = lane >> 4, l16 = lane & 15;
    const int wm = wave >> 1, wn = wave & 1;

    const int srow = t >> 2;
    const int sc   = ((t & 3) ^ ((t >> 3) & 3)) * 8;
    const ushort_t* Ag = Call + (size_t)(tileM + srow) * K + sc;
    const ushort_t* Bg = GWCt + (size_t)(tileN + srow) * K + sc;
    const int lo = t * 8;
    const int fro = (l16 * 4 + (quad ^ ((l16 >> 1) & 3))) * 8;

    floatx4 acc[4][4];
#pragma unroll
    for (int i = 0; i < 4; i++)
#pragma unroll
        for (int j = 0; j < 4; j++) acc[i][j] = (floatx4)0.f;

    for (int k0 = 0; k0 < K; k0 += 32) {
        gl_lds16(Ag + k0,                   &lA[lo]);
        gl_lds16(Ag + (size_t)64 * K + k0,  &lA[lo + 2048]);
        gl_lds16(Bg + k0,                   &lB[lo]);
        gl_lds16(Bg + (size_t)64 * K + k0,  &lB[lo + 2048]);
        __syncthreads();
        short8 af[4], bfr[4];
#pragma unroll
        for (int mi = 0; mi < 4; mi++)
            af[mi] = *(const short8*)&lA[(wm * 4 + mi) * 512 + fro];
#pragma unroll
        for (int ni = 0; ni < 4; ni++)
            bfr[ni] = *(const short8*)&lB[(wn * 4 + ni) * 512 + fro];
#pragma unroll
        for (int mi = 0; mi < 4; mi++)
#pragma unroll
            for (int ni = 0; ni < 4; ni++)
                acc[mi][ni] = __builtin_amdgcn_mfma_f32_16x16x32_bf16(
                    af[mi], bfr[ni], acc[mi][ni], 0, 0, 0);
        __syncthreads();
    }

    // ---- register-direct epilogue ----
    const int kk   = tileM >> 13;                          // choice index k (uniform per block)
    const int b0   = (tileM & 8191) + wm * 64 + quad * 4;  // batch row base (+mi*16+r)
    const int rowg = tileM + wm * 64 + quad * 4;           // Call row base (+mi*16+r)

    float gbv[4], obv[4];
    int   gcol[4];
#pragma unroll
    for (int ni = 0; ni < 4; ni++) {
        gcol[ni] = tileN + wn * 64 + ni * 16 + l16;
        gbv[ni]  = Gb[gcol[ni]];
        obv[ni]  = Ob[gcol[ni]];
    }

#pragma unroll
    for (int mi = 0; mi < 4; mi++) {
        float part[4] = {0.f, 0.f, 0.f, 0.f};
#pragma unroll
        for (int ni = 0; ni < 4; ni++) {
            const uint_t*   wpp = WPcat + (size_t)(b0 + mi * 16) * 1024 + gcol[ni];
            const ushort_t* ckp = Call  + (size_t)(rowg + mi * 16) * 1024 + gcol[ni];
#pragma unroll
            for (int r = 0; r < 4; r++) {
                const uint_t wpair = wpp[(size_t)r * 1024];
                const float wp  = bf2f((unsigned short)(wpair & 0xffffu));
                const float wpo = bf2f((unsigned short)(wpair >> 16));
                const float ck  = bf2f(ckp[(size_t)r * 1024]);
                const float x = wp + acc[mi][ni][r] + gbv[ni];   // WC stays fp32
                const float g = 1.f / (1.f + __expf(-x));
                part[r] += ck * g * (wpo + obv[ni]);
            }
        }
#pragma unroll
        for (int r = 0; r < 4; r++) {                    // reduce across 16-lane quad group
            part[r] += __shfl_xor(part[r], 1);
            part[r] += __shfl_xor(part[r], 2);
            part[r] += __shfl_xor(part[r], 4);
            part[r] += __shfl_xor(part[r], 8);
        }
        if (l16 == 0) {
#pragma unroll
            for (int r = 0; r < 4; r++)
                atomicAdd(&out[(size_t)(b0 + mi * 16 + r) * 4 + kk], part[r]);
        }
    }
}

extern "C" void kernel_launch(void* const* d_in, const int* in_sizes, int n_in,
                              void* d_out, int out_size, void* d_ws, size_t ws_size,
                              hipStream_t stream) {
    (void)in_sizes; (void)n_in; (void)out_size; (void)ws_size;
    const float* P   = (const float*)d_in[0];
    const float* C1  = (const float*)d_in[1];
    const float* C2  = (const float*)d_in[2];
    const float* C3  = (const float*)d_in[3];
    const float* C4  = (const float*)d_in[4];
    const float* GWP = (const float*)d_in[5];
    const float* GWC = (const float*)d_in[6];
    const float* Gb  = (const float*)d_in[7];
    const float* OW  = (const float*)d_in[8];
    const float* Ob  = (const float*)d_in[9];
    float* out = (float*)d_out;

    // workspace (bf16): Pb 16MiB | Call 64MiB | Wcat 4MiB | GWCt 2MiB | WPcat 32MiB
    char* ws = (char*)d_ws;
    ushort_t* Pb    = (ushort_t*)(ws);
    ushort_t* Call  = (ushort_t*)(ws + (16u << 20));
    ushort_t* Wcat  = (ushort_t*)(ws + (80u << 20));
    ushort_t* GWCt  = (ushort_t*)(ws + (84u << 20));
    ushort_t* WPcat = (ushort_t*)(ws + (86u << 20));

    prep_kernel<<<44064, 256, 0, stream>>>(P, C1, C2, C3, C4, GWP, OW, GWC,
                                           Pb, Call, Wcat, GWCt, out);
    gemmA<<<1024, 256, 0, stream>>>(Pb, Wcat, WPcat);
    gemmB_fused<<<2048, 256, 0, stream>>>(Call, GWCt, (const uint_t*)WPcat, Gb, Ob, out);
}